// Round 8
// baseline (194.057 us; speedup 1.0000x reference)
//
#include <hip/hip_runtime.h>
#include <hip/hip_bf16.h>

typedef __attribute__((ext_vector_type(8))) __bf16 bf16x8;
typedef __attribute__((ext_vector_type(16))) float f32x16;
typedef __attribute__((ext_vector_type(4))) unsigned int u32x4;

#define SCALE_L2E 14.4269504088896f // 10 * log2(e)
#define NTOT 32768

#define AS_GLOBAL __attribute__((address_space(1)))
#define AS_LDS    __attribute__((address_space(3)))

__device__ inline void async_copy16(const void* g, void* l) {
    __builtin_amdgcn_global_load_lds((const AS_GLOBAL void*)g, (AS_LDS void*)l, 16, 0, 0);
}

// MFMA via inline asm with AGPR-resident A-operand and accumulator.
// Forces af[] (128 regs) + accs out of the arch-VGPR pool -> VGPR ~56,
// AGPR ~192, total ~248 <= 256 at 2 waves/SIMD: no spill, full occupancy.
// (The intrinsic path lets the allocator keep af in VGPRs and spill - r3.)
__device__ inline void mfma_ag(f32x16& acc, const u32x4& a, const u32x4& b) {
    asm("v_mfma_f32_32x32x16_bf16 %0, %1, %2, %0"
        : "+a"(acc) : "a"(a), "v"(b));
}

// ---------------------------------------------------------------------------
// bf16 pack helpers (RNE)
// ---------------------------------------------------------------------------
__device__ inline unsigned int f2bf(float f) {
    unsigned int u = __builtin_bit_cast(unsigned int, f);
    u += 0x7fffu + ((u >> 16) & 1u);
    return u >> 16;
}

__device__ inline uint4 pack8(float4 x, float4 y, float s) {
    uint4 r;
    r.x = f2bf(x.x * s) | (f2bf(x.y * s) << 16);
    r.y = f2bf(x.z * s) | (f2bf(x.w * s) << 16);
    r.z = f2bf(y.x * s) | (f2bf(y.y * s) << 16);
    r.w = f2bf(y.z * s) | (f2bf(y.w * s) << 16);
    return r;
}

__device__ inline float dot8(float4 x, float4 y) {
    return x.x*y.x + x.y*y.y + x.z*y.z + x.w*y.w;
}

// ---------------------------------------------------------------------------
// Kernel 1: L2-normalize -> bf16 FRAGMENT-MAJOR + fp32 diag partials.
// E1 is PRE-SCALED by 10*log2(e) so gemm's epilogue is exp2(acc).
// ---------------------------------------------------------------------------
__global__ __launch_bounds__(256) void nrm_kernel(
        const float* __restrict__ A, const float* __restrict__ B,
        uint4* __restrict__ E1f, uint4* __restrict__ E2f,
        float* __restrict__ diagPart, float* __restrict__ scalars,
        unsigned int* __restrict__ counter) {
    const int tid = threadIdx.x, w = tid >> 6, l = tid & 63;
    const int q = l & 31, h = l >> 5;
    const int wid = blockIdx.x * 4 + w;            // 0..4095, 8 rows each

    const float4* A4 = (const float4*)A + ((size_t)wid * 8 + h) * 64 + q * 2;
    const float4* B4 = (const float4*)B + ((size_t)wid * 8 + h) * 64 + q * 2;

    float4 a[8], bb[8];
    #pragma unroll
    for (int i = 0; i < 4; ++i) {                  // all loads up front (MLP)
        a[2*i]    = A4[i * 128];
        a[2*i+1]  = A4[i * 128 + 1];
        bb[2*i]   = B4[i * 128];
        bb[2*i+1] = B4[i * 128 + 1];
    }

    float ddAcc = 0.f;
    #pragma unroll
    for (int i = 0; i < 4; ++i) {
        float sa = dot8(a[2*i], a[2*i]) + dot8(a[2*i+1], a[2*i+1]);
        float sb = dot8(bb[2*i], bb[2*i]) + dot8(bb[2*i+1], bb[2*i+1]);
        float dd = dot8(a[2*i], bb[2*i]) + dot8(a[2*i+1], bb[2*i+1]);
        #pragma unroll
        for (int off = 1; off <= 16; off <<= 1) {
            sa += __shfl_xor(sa, off);
            sb += __shfl_xor(sb, off);
            dd += __shfl_xor(dd, off);
        }
        const float ia = 1.0f / fmaxf(sqrtf(sa), 1e-12f);
        const float ib = 1.0f / fmaxf(sqrtf(sb), 1e-12f);
        if (q == 0) ddAcc += dd * ia * ib * 10.0f;

        const int n0 = wid * 8 + i * 2 + h;
        const size_t chunk = (size_t)(n0 >> 11) * 65536
                           + (size_t)((n0 & 2047) >> 5) * 1024
                           + (q >> 1) * 64 + (q & 1) * 32 + (n0 & 31);
        E1f[chunk] = pack8(a[2*i], a[2*i+1], ia * SCALE_L2E);  // pre-scaled
        E2f[chunk] = pack8(bb[2*i], bb[2*i+1], ib);
    }

    #pragma unroll
    for (int off = 1; off <= 32; off <<= 1) ddAcc += __shfl_xor(ddAcc, off);
    __shared__ float part[4];
    if (l == 0) part[w] = ddAcc;
    __syncthreads();
    if (tid == 0) diagPart[blockIdx.x] = part[0] + part[1] + part[2] + part[3];
    if (blockIdx.x == 0 && tid == 0) { scalars[0] = 0.f; *counter = 0u; }
}

// ---------------------------------------------------------------------------
// Kernel 2: fused GEMM + exp + row/col partials. 512 blocks, 4 waves.
// Block: 256 rows x 512 cols; wave: 64 rows (af0/af1 in AGPRS) x 512 cols.
// B staged 64-cols (32 KB) via global_load_lds, double-buffered; 8 barriers.
// Structure = r3 (best, 44.1us) with the register file split FORCED:
// af + accumulators in AGPRs via inline-asm MFMA ("a" constraints), arch
// VGPRs only for rowAcc/temps. Kills r3's 4MB scratch while keeping
// 2 blocks/CU (vs r7: compiler put af in VGPRs -> 240 arch VGPRs -> 1
// wave/SIMD -> 68us). s_nop guards cover accvgpr<->MFMA hazards that the
// intrinsic path would have handled.
// Pipelined: d1 is the deferred accumulator; its epilogue runs at the top
// of the NEXT iteration. d1 primed to -inf -> first epi adds exp2(-inf)=0.
// Raw v_exp_f32 epilogue; exp2(acc) with the -10 shift folded into fin.
// ---------------------------------------------------------------------------
__global__ __launch_bounds__(256, 2) void gemm_kernel(
        const bf16x8* __restrict__ E1f, const uint4* __restrict__ E2f,
        float* __restrict__ colPart, float* __restrict__ rowPart) {
    __shared__ bf16x8 Bbuf[2][2048];   // 2 x 32 KB (64 cols each)
    __shared__ float colLDS[2048];     // 4 per-wave slices of 512

    const int tid = threadIdx.x, w = tid >> 6, l = tid & 63;
    const int b = blockIdx.x & 15;             // XCD = b&7 (L2 pinning)
    const int ct = (blockIdx.x >> 4) & 3, rt = blockIdx.x >> 6;

    for (int i = l; i < 512; i += 64) colLDS[w * 512 + i] = 0.f;

    const uint4* Bb = E2f + (size_t)b * 65536 + (size_t)ct * 16384 + l;

    // stage 64-col group sg into Bbuf[buf]; wave w covers 8 chunk-rows
    auto stage = [&](int buf, int sg) {
        const uint4* src = Bb + (size_t)sg * 2048 + (w * 8) * 64;
        #pragma unroll
        for (int j = 0; j < 8; ++j)
            async_copy16(src + j * 64, &Bbuf[buf][(w * 8 + j) * 64]);
    };

    stage(0, 0);   // DMA queued first; A-loads land behind it

    // A fragments: two 32-row tiles, loaded to VGPR then pinned in AGPRs
    const u32x4* Af0 = (const u32x4*)(E1f + (size_t)b * 65536
                                      + (size_t)(rt * 8 + w * 2) * 1024) + l;
    const u32x4* Af1 = Af0 + 1024;
    u32x4 af0[16], af1[16];
    #pragma unroll
    for (int kt = 0; kt < 16; ++kt) { af0[kt] = Af0[kt * 64]; af1[kt] = Af1[kt * 64]; }

    float rowAcc0[16], rowAcc1[16];
    #pragma unroll
    for (int r = 0; r < 16; ++r) { rowAcc0[r] = 0.f; rowAcc1[r] = 0.f; }

    // interleaved dual-chain MFMA for one 32-col half (AGPR af + acc)
    auto mmpair = [&](f32x16& x0, f32x16& x1, const bf16x8* Bf) {
        #pragma unroll
        for (int r = 0; r < 16; ++r) { x0[r] = 0.f; x1[r] = 0.f; }
        asm volatile("s_nop 1");            // accvgpr_write -> MFMA-read-C
        __builtin_amdgcn_s_setprio(1);
        #pragma unroll
        for (int kt = 0; kt < 16; ++kt) {
            u32x4 bv = __builtin_bit_cast(u32x4, Bf[kt * 64]);
            mfma_ag(x0, af0[kt], bv);
            mfma_ag(x1, af1[kt], bv);
        }
        __builtin_amdgcn_s_setprio(0);
        asm volatile("s_nop 7\ns_nop 7\ns_nop 1");  // MFMA -> accvgpr_read
    };

    // epilogue for ONE finished accumulator (32 rows x 32 cols)
    auto epi = [&](const f32x16& c, float (&rAcc)[16], int slot) {
        float p = 0.f;
        #pragma unroll
        for (int r = 0; r < 16; ++r) {
            float e = __builtin_amdgcn_exp2f(c[r]);
            rAcc[r] += e;
            p += e;
        }
        p += __shfl_xor(p, 32);                 // fold 16-row halves
        if (l < 32) colLDS[w * 512 + slot * 32 + l] += p;
    };

    f32x16 c0, c1, d0, d1;
    #pragma unroll
    for (int r = 0; r < 16; ++r) d1[r] = -__builtin_inff();  // exp2 -> 0

    __syncthreads();   // stage(0) + A-frags complete

    for (int sg = 0; sg < 8; ++sg) {
        if (sg < 7) stage((sg + 1) & 1, sg + 1);
        const bf16x8* Bf = Bbuf[sg & 1] + l;

        mmpair(c0, c1, Bf);                       // half 0
        epi(d1, rowAcc1, (sg * 2 - 1) & 15);      // prev d1 (no copy): overlaps chain 0
        epi(c0, rowAcc0, sg * 2);

        mmpair(d0, d1, Bf + 1024);                // half 1 (re-inits d1 AFTER its epi)
        epi(c1, rowAcc1, sg * 2);                 // overlaps chain 1
        epi(d0, rowAcc0, sg * 2 + 1);
        // d1 stays live across the barrier; finished next iteration

        __syncthreads();
    }
    epi(d1, rowAcc1, 15);                         // drain

    // row sums: reduce across 32 column-lanes
    #pragma unroll
    for (int r = 0; r < 16; ++r) {
        #pragma unroll
        for (int off = 1; off <= 16; off <<= 1) {
            rowAcc0[r] += __shfl_xor(rowAcc0[r], off);
            rowAcc1[r] += __shfl_xor(rowAcc1[r], off);
        }
    }
    if ((l & 31) == 0) {
        // C/D layout: row = (r&3) + 8*(r>>2) + 4*(lane>>5); plain stores
        float* rs = rowPart + (size_t)(b * 4 + ct) * 2048 + rt * 256 + w * 64 + 4 * (l >> 5);
        #pragma unroll
        for (int r = 0; r < 16; ++r) {
            const int rl = (r & 3) + 8 * (r >> 2);
            rs[rl]      = rowAcc0[r];
            rs[rl + 32] = rowAcc1[r];
        }
    }

    __syncthreads();   // before cross-wave colLDS fold
    float* gcol = colPart + (size_t)((b * 4 + ct) * 8 + rt) * 512;
    for (int i = tid; i < 512; i += 256)
        gcol[i] = colLDS[i] + colLDS[512 + i] + colLDS[1024 + i] + colLDS[1536 + i];
}

// ---------------------------------------------------------------------------
// Kernel 3: fold partials, sum logs, last block finalizes.
// gemm computes exp2(acc) (no -SCALE_L2E shift); each of the 2*32768 log
// terms is larger by exactly 10.0, cancelling the former "+ 20.0f".
// ---------------------------------------------------------------------------
__global__ __launch_bounds__(256) void fin_kernel(
        const float* __restrict__ colPart, const float* __restrict__ rowPart,
        const float* __restrict__ diagPart, float* __restrict__ scalars,
        unsigned int* __restrict__ counter, float* __restrict__ out) {
    const int tid = threadIdx.x;
    float s = 0.f;
    #pragma unroll
    for (int k = 0; k < 2; ++k) {
        const int g = blockIdx.x * 512 + k * 256 + tid;
        // column g: b = g>>11, ct = (g>>9)&3, c = g&511
        const float* cp = colPart + (size_t)(((g >> 11) * 4 + ((g >> 9) & 3)) * 8) * 512 + (g & 511);
        float cs = 0.f;
        #pragma unroll
        for (int rt = 0; rt < 8; ++rt) cs += cp[rt * 512];
        // row g: b = g>>11, r = g&2047
        const float* rp = rowPart + (size_t)(g >> 11) * 4 * 2048 + (g & 2047);
        float rsum = rp[0] + rp[2048] + rp[4096] + rp[6144];
        s += logf(cs) + logf(rsum);
    }
    #pragma unroll
    for (int off = 1; off <= 32; off <<= 1) s += __shfl_xor(s, off);
    __shared__ float part[4];
    __shared__ unsigned int lastFlag;
    if ((tid & 63) == 0) part[tid >> 6] = s;
    __syncthreads();
    if (tid == 0) {
        atomicAdd(&scalars[0], part[0] + part[1] + part[2] + part[3]);
        __threadfence();
        lastFlag = (atomicAdd(counter, 1u) == 63u) ? 1u : 0u;
    }
    __syncthreads();
    if (lastFlag) {
        float d = diagPart[tid] + diagPart[tid + 256]
                + diagPart[tid + 512] + diagPart[tid + 768];
        #pragma unroll
        for (int off = 1; off <= 32; off <<= 1) d += __shfl_xor(d, off);
        if ((tid & 63) == 0) part[tid >> 6] = d;
        __syncthreads();
        if (tid == 0) {
            const float diag = part[0] + part[1] + part[2] + part[3];
            const float logSum = atomicAdd(&scalars[0], 0.f);  // coherent read
            out[0] = (logSum - 2.0f * diag) / (float)NTOT;
        }
    }
}

// ---------------------------------------------------------------------------
extern "C" void kernel_launch(void* const* d_in, const int* in_sizes, int n_in,
                              void* d_out, int out_size, void* d_ws, size_t ws_size,
                              hipStream_t stream) {
    const float* A = (const float*)d_in[0];
    const float* B = (const float*)d_in[1];

    char* w = (char*)d_ws;
    uint4* E1f = (uint4*)w;                                    // 16 MB
    uint4* E2f = (uint4*)(w + (size_t)16 * 1024 * 1024);       // 16 MB
    float* colPart = (float*)(w + (size_t)32 * 1024 * 1024);   // 262144 f (1 MB)
    float* rowPart = colPart + 262144;                         // 131072 f (0.5 MB)
    float* diagPart = rowPart + 131072;                        // 1024 f
    float* scalars = diagPart + 1024;                          // [logSum]
    unsigned int* counter = (unsigned int*)(scalars + 1);

    hipLaunchKernelGGL(nrm_kernel, dim3(1024), dim3(256), 0, stream,
                       A, B, E1f, E2f, diagPart, scalars, counter);
    hipLaunchKernelGGL(gemm_kernel, dim3(512), dim3(256), 0, stream,
                       (const bf16x8*)E1f, (const uint4*)E2f, colPart, rowPart);
    hipLaunchKernelGGL(fin_kernel, dim3(64), dim3(256), 0, stream,
                       colPart, rowPart, diagPart, scalars, counter, (float*)d_out);
}

// Round 9
// 167.581 us; speedup vs baseline: 1.1580x; 1.1580x over previous
//
#include <hip/hip_runtime.h>
#include <hip/hip_bf16.h>

typedef __attribute__((ext_vector_type(8))) __bf16 bf16x8;
typedef __attribute__((ext_vector_type(16))) float f32x16;
typedef __attribute__((ext_vector_type(4))) unsigned int u32x4;

#define SCALE_L2E 14.4269504088896f // 10 * log2(e)
#define NTOT 32768

#define AS_GLOBAL __attribute__((address_space(1)))
#define AS_LDS    __attribute__((address_space(3)))

__device__ inline void async_copy16(const void* g, void* l) {
    __builtin_amdgcn_global_load_lds((const AS_GLOBAL void*)g, (AS_LDS void*)l, 16, 0, 0);
}

// MFMA: A-operand from AGPR ("a"), accumulator in VGPR ("+v"), B from VGPR.
// This pins af0/af1 (128 regs, write-once) into the AGPR half of the file
// while the VALU-read accumulators stay VGPR-resident -> no cross-file
// copies in the hot loop. r8's all-AGPR version overflowed the 128-AGPR
// half (af 128 + accs 64 = 192) -> AGPR scratch spill, 88us.
__device__ inline void mfma_av(f32x16& acc, const u32x4& a, const u32x4& b) {
    asm("v_mfma_f32_32x32x16_bf16 %0, %1, %2, %0"
        : "+v"(acc) : "a"(a), "v"(b));
}

// ---------------------------------------------------------------------------
// bf16 pack helpers (RNE)
// ---------------------------------------------------------------------------
__device__ inline unsigned int f2bf(float f) {
    unsigned int u = __builtin_bit_cast(unsigned int, f);
    u += 0x7fffu + ((u >> 16) & 1u);
    return u >> 16;
}

__device__ inline uint4 pack8(float4 x, float4 y, float s) {
    uint4 r;
    r.x = f2bf(x.x * s) | (f2bf(x.y * s) << 16);
    r.y = f2bf(x.z * s) | (f2bf(x.w * s) << 16);
    r.z = f2bf(y.x * s) | (f2bf(y.y * s) << 16);
    r.w = f2bf(y.z * s) | (f2bf(y.w * s) << 16);
    return r;
}

__device__ inline float dot8(float4 x, float4 y) {
    return x.x*y.x + x.y*y.y + x.z*y.z + x.w*y.w;
}

// ---------------------------------------------------------------------------
// Kernel 1: L2-normalize -> bf16 FRAGMENT-MAJOR + fp32 diag partials.
// E1 is PRE-SCALED by 10*log2(e) so gemm's epilogue is exp2(acc).
// ---------------------------------------------------------------------------
__global__ __launch_bounds__(256) void nrm_kernel(
        const float* __restrict__ A, const float* __restrict__ B,
        uint4* __restrict__ E1f, uint4* __restrict__ E2f,
        float* __restrict__ diagPart, float* __restrict__ scalars,
        unsigned int* __restrict__ counter) {
    const int tid = threadIdx.x, w = tid >> 6, l = tid & 63;
    const int q = l & 31, h = l >> 5;
    const int wid = blockIdx.x * 4 + w;            // 0..4095, 8 rows each

    const float4* A4 = (const float4*)A + ((size_t)wid * 8 + h) * 64 + q * 2;
    const float4* B4 = (const float4*)B + ((size_t)wid * 8 + h) * 64 + q * 2;

    float4 a[8], bb[8];
    #pragma unroll
    for (int i = 0; i < 4; ++i) {                  // all loads up front (MLP)
        a[2*i]    = A4[i * 128];
        a[2*i+1]  = A4[i * 128 + 1];
        bb[2*i]   = B4[i * 128];
        bb[2*i+1] = B4[i * 128 + 1];
    }

    float ddAcc = 0.f;
    #pragma unroll
    for (int i = 0; i < 4; ++i) {
        float sa = dot8(a[2*i], a[2*i]) + dot8(a[2*i+1], a[2*i+1]);
        float sb = dot8(bb[2*i], bb[2*i]) + dot8(bb[2*i+1], bb[2*i+1]);
        float dd = dot8(a[2*i], bb[2*i]) + dot8(a[2*i+1], bb[2*i+1]);
        #pragma unroll
        for (int off = 1; off <= 16; off <<= 1) {
            sa += __shfl_xor(sa, off);
            sb += __shfl_xor(sb, off);
            dd += __shfl_xor(dd, off);
        }
        const float ia = 1.0f / fmaxf(sqrtf(sa), 1e-12f);
        const float ib = 1.0f / fmaxf(sqrtf(sb), 1e-12f);
        if (q == 0) ddAcc += dd * ia * ib * 10.0f;

        const int n0 = wid * 8 + i * 2 + h;
        const size_t chunk = (size_t)(n0 >> 11) * 65536
                           + (size_t)((n0 & 2047) >> 5) * 1024
                           + (q >> 1) * 64 + (q & 1) * 32 + (n0 & 31);
        E1f[chunk] = pack8(a[2*i], a[2*i+1], ia * SCALE_L2E);  // pre-scaled
        E2f[chunk] = pack8(bb[2*i], bb[2*i+1], ib);
    }

    #pragma unroll
    for (int off = 1; off <= 32; off <<= 1) ddAcc += __shfl_xor(ddAcc, off);
    __shared__ float part[4];
    if (l == 0) part[w] = ddAcc;
    __syncthreads();
    if (tid == 0) diagPart[blockIdx.x] = part[0] + part[1] + part[2] + part[3];
    if (blockIdx.x == 0 && tid == 0) { scalars[0] = 0.f; *counter = 0u; }
}

// ---------------------------------------------------------------------------
// Kernel 2: fused GEMM + exp + row/col partials. 512 blocks, 4 waves.
// Block: 256 rows x 512 cols; wave: 64 rows x 512 cols. Structure = r3
// (best, 44.1us) with the register-file split FORCED the right way round:
//   AGPR half (128): af0+af1 = 128 exactly (write-once A-operands)
//   VGPR half (128): 4 accs (64) + rowAcc (32) + temps (~25) = ~121
// -> no spill on either side, 2 blocks/CU, epilogue reads accs without
// cross-file copies. s_nop guards cover the inline-asm MFMA hazards the
// hazard recognizer can't see (r8 proved them numerically sufficient).
// Pipelined: d1 is the deferred accumulator; its epilogue runs at the top
// of the NEXT iteration. d1 primed to -inf -> first epi adds exp2(-inf)=0.
// Raw v_exp_f32 epilogue; exp2(acc) with the -10 shift folded into fin.
// ---------------------------------------------------------------------------
__global__ __launch_bounds__(256, 2) void gemm_kernel(
        const bf16x8* __restrict__ E1f, const uint4* __restrict__ E2f,
        float* __restrict__ colPart, float* __restrict__ rowPart) {
    __shared__ bf16x8 Bbuf[2][2048];   // 2 x 32 KB (64 cols each)
    __shared__ float colLDS[2048];     // 4 per-wave slices of 512

    const int tid = threadIdx.x, w = tid >> 6, l = tid & 63;
    const int b = blockIdx.x & 15;             // XCD = b&7 (L2 pinning)
    const int ct = (blockIdx.x >> 4) & 3, rt = blockIdx.x >> 6;

    for (int i = l; i < 512; i += 64) colLDS[w * 512 + i] = 0.f;

    const uint4* Bb = E2f + (size_t)b * 65536 + (size_t)ct * 16384 + l;

    // stage 64-col group sg into Bbuf[buf]; wave w covers 8 chunk-rows
    auto stage = [&](int buf, int sg) {
        const uint4* src = Bb + (size_t)sg * 2048 + (w * 8) * 64;
        #pragma unroll
        for (int j = 0; j < 8; ++j)
            async_copy16(src + j * 64, &Bbuf[buf][(w * 8 + j) * 64]);
    };

    stage(0, 0);   // DMA queued first; A-loads land behind it

    // A fragments: two 32-row tiles; loaded once, pinned to AGPRs by the
    // "a" constraint on every use (one v->a copy per reg at def point).
    const u32x4* Af0 = (const u32x4*)(E1f + (size_t)b * 65536
                                      + (size_t)(rt * 8 + w * 2) * 1024) + l;
    const u32x4* Af1 = Af0 + 1024;
    u32x4 af0[16], af1[16];
    #pragma unroll
    for (int kt = 0; kt < 16; ++kt) { af0[kt] = Af0[kt * 64]; af1[kt] = Af1[kt * 64]; }

    float rowAcc0[16], rowAcc1[16];
    #pragma unroll
    for (int r = 0; r < 16; ++r) { rowAcc0[r] = 0.f; rowAcc1[r] = 0.f; }

    // interleaved dual-chain MFMA for one 32-col half (AGPR af, VGPR acc)
    auto mmpair = [&](f32x16& x0, f32x16& x1, const bf16x8* Bf) {
        #pragma unroll
        for (int r = 0; r < 16; ++r) { x0[r] = 0.f; x1[r] = 0.f; }
        asm volatile("s_nop 1");            // v_mov acc-init -> MFMA read-C
        __builtin_amdgcn_s_setprio(1);
        #pragma unroll
        for (int kt = 0; kt < 16; ++kt) {
            u32x4 bv = __builtin_bit_cast(u32x4, Bf[kt * 64]);
            mfma_av(x0, af0[kt], bv);
            mfma_av(x1, af1[kt], bv);
        }
        __builtin_amdgcn_s_setprio(0);
        asm volatile("s_nop 7\ns_nop 7\ns_nop 1");  // MFMA -> VALU read of acc
    };

    // epilogue for ONE finished accumulator (32 rows x 32 cols)
    auto epi = [&](const f32x16& c, float (&rAcc)[16], int slot) {
        float p = 0.f;
        #pragma unroll
        for (int r = 0; r < 16; ++r) {
            float e = __builtin_amdgcn_exp2f(c[r]);
            rAcc[r] += e;
            p += e;
        }
        p += __shfl_xor(p, 32);                 // fold 16-row halves
        if (l < 32) colLDS[w * 512 + slot * 32 + l] += p;
    };

    f32x16 c0, c1, d0, d1;
    #pragma unroll
    for (int r = 0; r < 16; ++r) d1[r] = -__builtin_inff();  // exp2 -> 0

    __syncthreads();   // stage(0) + A-frags complete

    for (int sg = 0; sg < 8; ++sg) {
        if (sg < 7) stage((sg + 1) & 1, sg + 1);
        const bf16x8* Bf = Bbuf[sg & 1] + l;

        mmpair(c0, c1, Bf);                       // half 0
        epi(d1, rowAcc1, (sg * 2 - 1) & 15);      // prev d1 (no copy): overlaps chain 0
        epi(c0, rowAcc0, sg * 2);

        mmpair(d0, d1, Bf + 1024);                // half 1 (re-inits d1 AFTER its epi)
        epi(c1, rowAcc1, sg * 2);                 // overlaps chain 1
        epi(d0, rowAcc0, sg * 2 + 1);
        // d1 stays live across the barrier; finished next iteration

        __syncthreads();
    }
    epi(d1, rowAcc1, 15);                         // drain

    // row sums: reduce across 32 column-lanes
    #pragma unroll
    for (int r = 0; r < 16; ++r) {
        #pragma unroll
        for (int off = 1; off <= 16; off <<= 1) {
            rowAcc0[r] += __shfl_xor(rowAcc0[r], off);
            rowAcc1[r] += __shfl_xor(rowAcc1[r], off);
        }
    }
    if ((l & 31) == 0) {
        // C/D layout: row = (r&3) + 8*(r>>2) + 4*(lane>>5); plain stores
        float* rs = rowPart + (size_t)(b * 4 + ct) * 2048 + rt * 256 + w * 64 + 4 * (l >> 5);
        #pragma unroll
        for (int r = 0; r < 16; ++r) {
            const int rl = (r & 3) + 8 * (r >> 2);
            rs[rl]      = rowAcc0[r];
            rs[rl + 32] = rowAcc1[r];
        }
    }

    __syncthreads();   // before cross-wave colLDS fold
    float* gcol = colPart + (size_t)((b * 4 + ct) * 8 + rt) * 512;
    for (int i = tid; i < 512; i += 256)
        gcol[i] = colLDS[i] + colLDS[512 + i] + colLDS[1024 + i] + colLDS[1536 + i];
}

// ---------------------------------------------------------------------------
// Kernel 3: fold partials, sum logs, last block finalizes.
// gemm computes exp2(acc) (no -SCALE_L2E shift); each of the 2*32768 log
// terms is larger by exactly 10.0, cancelling the former "+ 20.0f".
// ---------------------------------------------------------------------------
__global__ __launch_bounds__(256) void fin_kernel(
        const float* __restrict__ colPart, const float* __restrict__ rowPart,
        const float* __restrict__ diagPart, float* __restrict__ scalars,
        unsigned int* __restrict__ counter, float* __restrict__ out) {
    const int tid = threadIdx.x;
    float s = 0.f;
    #pragma unroll
    for (int k = 0; k < 2; ++k) {
        const int g = blockIdx.x * 512 + k * 256 + tid;
        // column g: b = g>>11, ct = (g>>9)&3, c = g&511
        const float* cp = colPart + (size_t)(((g >> 11) * 4 + ((g >> 9) & 3)) * 8) * 512 + (g & 511);
        float cs = 0.f;
        #pragma unroll
        for (int rt = 0; rt < 8; ++rt) cs += cp[rt * 512];
        // row g: b = g>>11, r = g&2047
        const float* rp = rowPart + (size_t)(g >> 11) * 4 * 2048 + (g & 2047);
        float rsum = rp[0] + rp[2048] + rp[4096] + rp[6144];
        s += logf(cs) + logf(rsum);
    }
    #pragma unroll
    for (int off = 1; off <= 32; off <<= 1) s += __shfl_xor(s, off);
    __shared__ float part[4];
    __shared__ unsigned int lastFlag;
    if ((tid & 63) == 0) part[tid >> 6] = s;
    __syncthreads();
    if (tid == 0) {
        atomicAdd(&scalars[0], part[0] + part[1] + part[2] + part[3]);
        __threadfence();
        lastFlag = (atomicAdd(counter, 1u) == 63u) ? 1u : 0u;
    }
    __syncthreads();
    if (lastFlag) {
        float d = diagPart[tid] + diagPart[tid + 256]
                + diagPart[tid + 512] + diagPart[tid + 768];
        #pragma unroll
        for (int off = 1; off <= 32; off <<= 1) d += __shfl_xor(d, off);
        if ((tid & 63) == 0) part[tid >> 6] = d;
        __syncthreads();
        if (tid == 0) {
            const float diag = part[0] + part[1] + part[2] + part[3];
            const float logSum = atomicAdd(&scalars[0], 0.f);  // coherent read
            out[0] = (logSum - 2.0f * diag) / (float)NTOT;
        }
    }
}

// ---------------------------------------------------------------------------
extern "C" void kernel_launch(void* const* d_in, const int* in_sizes, int n_in,
                              void* d_out, int out_size, void* d_ws, size_t ws_size,
                              hipStream_t stream) {
    const float* A = (const float*)d_in[0];
    const float* B = (const float*)d_in[1];

    char* w = (char*)d_ws;
    uint4* E1f = (uint4*)w;                                    // 16 MB
    uint4* E2f = (uint4*)(w + (size_t)16 * 1024 * 1024);       // 16 MB
    float* colPart = (float*)(w + (size_t)32 * 1024 * 1024);   // 262144 f (1 MB)
    float* rowPart = colPart + 262144;                         // 131072 f (0.5 MB)
    float* diagPart = rowPart + 131072;                        // 1024 f
    float* scalars = diagPart + 1024;                          // [logSum]
    unsigned int* counter = (unsigned int*)(scalars + 1);

    hipLaunchKernelGGL(nrm_kernel, dim3(1024), dim3(256), 0, stream,
                       A, B, E1f, E2f, diagPart, scalars, counter);
    hipLaunchKernelGGL(gemm_kernel, dim3(512), dim3(256), 0, stream,
                       (const bf16x8*)E1f, (const uint4*)E2f, colPart, rowPart);
    hipLaunchKernelGGL(fin_kernel, dim3(64), dim3(256), 0, stream,
                       colPart, rowPart, diagPart, scalars, counter, (float*)d_out);
}

// Round 10
// 139.975 us; speedup vs baseline: 1.3864x; 1.1972x over previous
//
#include <hip/hip_runtime.h>
#include <hip/hip_bf16.h>

typedef __attribute__((ext_vector_type(8))) __bf16 bf16x8;
typedef __attribute__((ext_vector_type(16))) float f32x16;

#define SCALE_L2E 14.4269504088896f // 10 * log2(e)
#define NTOT 32768

#define AS_GLOBAL __attribute__((address_space(1)))
#define AS_LDS    __attribute__((address_space(3)))

__device__ inline void async_copy16(const void* g, void* l) {
    __builtin_amdgcn_global_load_lds((const AS_GLOBAL void*)g, (AS_LDS void*)l, 16, 0, 0);
}

// ---------------------------------------------------------------------------
// bf16 pack helpers (RNE)
// ---------------------------------------------------------------------------
__device__ inline unsigned int f2bf(float f) {
    unsigned int u = __builtin_bit_cast(unsigned int, f);
    u += 0x7fffu + ((u >> 16) & 1u);
    return u >> 16;
}

__device__ inline uint4 pack8(float4 x, float4 y, float s) {
    uint4 r;
    r.x = f2bf(x.x * s) | (f2bf(x.y * s) << 16);
    r.y = f2bf(x.z * s) | (f2bf(x.w * s) << 16);
    r.z = f2bf(y.x * s) | (f2bf(y.y * s) << 16);
    r.w = f2bf(y.z * s) | (f2bf(y.w * s) << 16);
    return r;
}

__device__ inline float dot8(float4 x, float4 y) {
    return x.x*y.x + x.y*y.y + x.z*y.z + x.w*y.w;
}

// ---------------------------------------------------------------------------
// Kernel 1: L2-normalize -> bf16 FRAGMENT-MAJOR + fp32 diag partials.
// E1 is PRE-SCALED by 10*log2(e) so gemm's epilogue is exp2(acc).
//
// NEW: coalesced E-stores via 32KB LDS transpose. The direct fragment-major
// store was a 16B/lane scatter at 512B stride (64 txns/wave-store on 32 MB).
// A block covers exactly one 32-row fragment group (rows blockIdx*32+w*8+
// i*2+h = 0..31), whose global span is uint4[blockIdx*1024 .. +1024).
// Produce phase writes packed uint4s to XOR-swizzled LDS (idx^((idx>>5)&7),
// bank-spread both phases); write phase streams 2x16KB out fully coalesced.
// Contents bit-identical to before; gemm layout untouched.
// ---------------------------------------------------------------------------
__global__ __launch_bounds__(256) void nrm_kernel(
        const float* __restrict__ A, const float* __restrict__ B,
        uint4* __restrict__ E1f, uint4* __restrict__ E2f,
        float* __restrict__ diagPart, float* __restrict__ scalars,
        unsigned int* __restrict__ counter) {
    __shared__ uint4 E1lds[1024];   // 16 KB
    __shared__ uint4 E2lds[1024];   // 16 KB
    __shared__ float part[4];

    const int tid = threadIdx.x, w = tid >> 6, l = tid & 63;
    const int q = l & 31, h = l >> 5;
    const int wid = blockIdx.x * 4 + w;            // 0..4095, 8 rows each

    const float4* A4 = (const float4*)A + ((size_t)wid * 8 + h) * 64 + q * 2;
    const float4* B4 = (const float4*)B + ((size_t)wid * 8 + h) * 64 + q * 2;

    float4 a[8], bb[8];
    #pragma unroll
    for (int i = 0; i < 4; ++i) {                  // all loads up front (MLP)
        a[2*i]    = A4[i * 128];
        a[2*i+1]  = A4[i * 128 + 1];
        bb[2*i]   = B4[i * 128];
        bb[2*i+1] = B4[i * 128 + 1];
    }

    float ddAcc = 0.f;
    #pragma unroll
    for (int i = 0; i < 4; ++i) {
        float sa = dot8(a[2*i], a[2*i]) + dot8(a[2*i+1], a[2*i+1]);
        float sb = dot8(bb[2*i], bb[2*i]) + dot8(bb[2*i+1], bb[2*i+1]);
        float dd = dot8(a[2*i], bb[2*i]) + dot8(a[2*i+1], bb[2*i+1]);
        #pragma unroll
        for (int off = 1; off <= 16; off <<= 1) {
            sa += __shfl_xor(sa, off);
            sb += __shfl_xor(sb, off);
            dd += __shfl_xor(dd, off);
        }
        const float ia = 1.0f / fmaxf(sqrtf(sa), 1e-12f);
        const float ib = 1.0f / fmaxf(sqrtf(sb), 1e-12f);
        if (q == 0) ddAcc += dd * ia * ib * 10.0f;

        // LDS transpose staging: idx within this block's 32-row group
        const int row32 = w * 8 + i * 2 + h;                 // 0..31
        const int idx   = (q >> 1) * 64 + (q & 1) * 32 + row32;
        const int idxs  = idx ^ ((idx >> 5) & 7);            // bank swizzle
        E1lds[idxs] = pack8(a[2*i], a[2*i+1], ia * SCALE_L2E);  // pre-scaled
        E2lds[idxs] = pack8(bb[2*i], bb[2*i+1], ib);
    }

    #pragma unroll
    for (int off = 1; off <= 32; off <<= 1) ddAcc += __shfl_xor(ddAcc, off);
    if (l == 0) part[w] = ddAcc;
    __syncthreads();   // part[] + E-lds complete

    // coalesced write-out: this block's group is uint4[blockIdx*1024 ..)
    {
        uint4* g1 = E1f + (size_t)blockIdx.x * 1024;
        uint4* g2 = E2f + (size_t)blockIdx.x * 1024;
        #pragma unroll
        for (int j = 0; j < 4; ++j) {
            const int t = j * 256 + tid;
            const int ts = t ^ ((t >> 5) & 7);
            g1[t] = E1lds[ts];
            g2[t] = E2lds[ts];
        }
    }

    if (tid == 0) diagPart[blockIdx.x] = part[0] + part[1] + part[2] + part[3];
    if (blockIdx.x == 0 && tid == 0) { scalars[0] = 0.f; *counter = 0u; }
}

// ---------------------------------------------------------------------------
// Kernel 2: fused GEMM + exp + row/col partials. 512 blocks, 4 waves.
// Block: 256 rows x 512 cols; wave: 64 rows (af0/af1 in regs) x 512 cols.
// B staged 64-cols (32 KB) via global_load_lds, double-buffered; 8 barriers.
// EXACT r3 source (measured 44.1us): intrinsic MFMAs, (256,2) bounds, 4MB
// spill tolerated -- rounds 4-9 proved every "cure" (wave resize, uncapped
// regs, asm AGPR pinning) costs more than the spill itself.
// Pipelined: d1 is the deferred accumulator; its epilogue runs at the top
// of the NEXT iteration. d1 primed to -inf -> first epi adds exp2(-inf)=0.
// Raw v_exp_f32 epilogue; exp2(acc) with the -10 shift folded into fin.
// ---------------------------------------------------------------------------
__global__ __launch_bounds__(256, 2) void gemm_kernel(
        const bf16x8* __restrict__ E1f, const uint4* __restrict__ E2f,
        float* __restrict__ colPart, float* __restrict__ rowPart) {
    __shared__ bf16x8 Bbuf[2][2048];   // 2 x 32 KB (64 cols each)
    __shared__ float colLDS[2048];     // 4 per-wave slices of 512

    const int tid = threadIdx.x, w = tid >> 6, l = tid & 63;
    const int b = blockIdx.x & 15;             // XCD = b&7 (L2 pinning)
    const int ct = (blockIdx.x >> 4) & 3, rt = blockIdx.x >> 6;

    for (int i = l; i < 512; i += 64) colLDS[w * 512 + i] = 0.f;

    const uint4* Bb = E2f + (size_t)b * 65536 + (size_t)ct * 16384 + l;

    // stage 64-col group sg into Bbuf[buf]; wave w covers 8 chunk-rows
    auto stage = [&](int buf, int sg) {
        const uint4* src = Bb + (size_t)sg * 2048 + (w * 8) * 64;
        #pragma unroll
        for (int j = 0; j < 8; ++j)
            async_copy16(src + j * 64, &Bbuf[buf][(w * 8 + j) * 64]);
    };

    stage(0, 0);   // DMA queued first; A-loads land behind it

    // A fragments: two 32-row tiles (fragment-major, coalesced 1KB loads)
    const bf16x8* Af0 = E1f + (size_t)b * 65536 + (size_t)(rt * 8 + w * 2) * 1024 + l;
    const bf16x8* Af1 = Af0 + 1024;
    bf16x8 af0[16], af1[16];
    #pragma unroll
    for (int kt = 0; kt < 16; ++kt) { af0[kt] = Af0[kt * 64]; af1[kt] = Af1[kt * 64]; }

    float rowAcc0[16], rowAcc1[16];
    #pragma unroll
    for (int r = 0; r < 16; ++r) { rowAcc0[r] = 0.f; rowAcc1[r] = 0.f; }

    // interleaved dual-chain MFMA for one 32-col half
    auto mmpair = [&](f32x16& x0, f32x16& x1, const bf16x8* Bf) {
        #pragma unroll
        for (int r = 0; r < 16; ++r) { x0[r] = 0.f; x1[r] = 0.f; }
        __builtin_amdgcn_s_setprio(1);
        #pragma unroll
        for (int kt = 0; kt < 16; ++kt) {
            bf16x8 bfrag = Bf[kt * 64];
            x0 = __builtin_amdgcn_mfma_f32_32x32x16_bf16(af0[kt], bfrag, x0, 0, 0, 0);
            x1 = __builtin_amdgcn_mfma_f32_32x32x16_bf16(af1[kt], bfrag, x1, 0, 0, 0);
        }
        __builtin_amdgcn_s_setprio(0);
    };

    // epilogue for ONE finished accumulator (32 rows x 32 cols)
    auto epi = [&](const f32x16& c, float (&rAcc)[16], int slot) {
        float p = 0.f;
        #pragma unroll
        for (int r = 0; r < 16; ++r) {
            float e = __builtin_amdgcn_exp2f(c[r]);
            rAcc[r] += e;
            p += e;
        }
        p += __shfl_xor(p, 32);                 // fold 16-row halves
        if (l < 32) colLDS[w * 512 + slot * 32 + l] += p;
    };

    f32x16 c0, c1, d0, d1;
    #pragma unroll
    for (int r = 0; r < 16; ++r) d1[r] = -__builtin_inff();  // exp2 -> 0

    __syncthreads();   // stage(0) + A-frags complete

    for (int sg = 0; sg < 8; ++sg) {
        if (sg < 7) stage((sg + 1) & 1, sg + 1);
        const bf16x8* Bf = Bbuf[sg & 1] + l;

        mmpair(c0, c1, Bf);                       // half 0
        epi(d1, rowAcc1, (sg * 2 - 1) & 15);      // prev d1 (no copy): overlaps chain 0
        epi(c0, rowAcc0, sg * 2);

        mmpair(d0, d1, Bf + 1024);                // half 1 (re-inits d1 AFTER its epi)
        epi(c1, rowAcc1, sg * 2);                 // overlaps chain 1
        epi(d0, rowAcc0, sg * 2 + 1);
        // d1 stays live across the barrier; finished next iteration

        __syncthreads();
    }
    epi(d1, rowAcc1, 15);                         // drain

    // row sums: reduce across 32 column-lanes
    #pragma unroll
    for (int r = 0; r < 16; ++r) {
        #pragma unroll
        for (int off = 1; off <= 16; off <<= 1) {
            rowAcc0[r] += __shfl_xor(rowAcc0[r], off);
            rowAcc1[r] += __shfl_xor(rowAcc1[r], off);
        }
    }
    if ((l & 31) == 0) {
        // C/D layout: row = (r&3) + 8*(r>>2) + 4*(lane>>5); plain stores
        float* rs = rowPart + (size_t)(b * 4 + ct) * 2048 + rt * 256 + w * 64 + 4 * (l >> 5);
        #pragma unroll
        for (int r = 0; r < 16; ++r) {
            const int rl = (r & 3) + 8 * (r >> 2);
            rs[rl]      = rowAcc0[r];
            rs[rl + 32] = rowAcc1[r];
        }
    }

    __syncthreads();   // before cross-wave colLDS fold
    float* gcol = colPart + (size_t)((b * 4 + ct) * 8 + rt) * 512;
    for (int i = tid; i < 512; i += 256)
        gcol[i] = colLDS[i] + colLDS[512 + i] + colLDS[1024 + i] + colLDS[1536 + i];
}

// ---------------------------------------------------------------------------
// Kernel 3: fold partials, sum logs, last block finalizes.
// gemm computes exp2(acc) (no -SCALE_L2E shift); each of the 2*32768 log
// terms is larger by exactly 10.0, cancelling the former "+ 20.0f".
// ---------------------------------------------------------------------------
__global__ __launch_bounds__(256) void fin_kernel(
        const float* __restrict__ colPart, const float* __restrict__ rowPart,
        const float* __restrict__ diagPart, float* __restrict__ scalars,
        unsigned int* __restrict__ counter, float* __restrict__ out) {
    const int tid = threadIdx.x;
    float s = 0.f;
    #pragma unroll
    for (int k = 0; k < 2; ++k) {
        const int g = blockIdx.x * 512 + k * 256 + tid;
        // column g: b = g>>11, ct = (g>>9)&3, c = g&511
        const float* cp = colPart + (size_t)(((g >> 11) * 4 + ((g >> 9) & 3)) * 8) * 512 + (g & 511);
        float cs = 0.f;
        #pragma unroll
        for (int rt = 0; rt < 8; ++rt) cs += cp[rt * 512];
        // row g: b = g>>11, r = g&2047
        const float* rp = rowPart + (size_t)(g >> 11) * 4 * 2048 + (g & 2047);
        float rsum = rp[0] + rp[2048] + rp[4096] + rp[6144];
        s += logf(cs) + logf(rsum);
    }
    #pragma unroll
    for (int off = 1; off <= 32; off <<= 1) s += __shfl_xor(s, off);
    __shared__ float part[4];
    __shared__ unsigned int lastFlag;
    if ((tid & 63) == 0) part[tid >> 6] = s;
    __syncthreads();
    if (tid == 0) {
        atomicAdd(&scalars[0], part[0] + part[1] + part[2] + part[3]);
        __threadfence();
        lastFlag = (atomicAdd(counter, 1u) == 63u) ? 1u : 0u;
    }
    __syncthreads();
    if (lastFlag) {
        float d = diagPart[tid] + diagPart[tid + 256]
                + diagPart[tid + 512] + diagPart[tid + 768];
        #pragma unroll
        for (int off = 1; off <= 32; off <<= 1) d += __shfl_xor(d, off);
        if ((tid & 63) == 0) part[tid >> 6] = d;
        __syncthreads();
        if (tid == 0) {
            const float diag = part[0] + part[1] + part[2] + part[3];
            const float logSum = atomicAdd(&scalars[0], 0.f);  // coherent read
            out[0] = (logSum - 2.0f * diag) / (float)NTOT;
        }
    }
}

// ---------------------------------------------------------------------------
extern "C" void kernel_launch(void* const* d_in, const int* in_sizes, int n_in,
                              void* d_out, int out_size, void* d_ws, size_t ws_size,
                              hipStream_t stream) {
    const float* A = (const float*)d_in[0];
    const float* B = (const float*)d_in[1];

    char* w = (char*)d_ws;
    uint4* E1f = (uint4*)w;                                    // 16 MB
    uint4* E2f = (uint4*)(w + (size_t)16 * 1024 * 1024);       // 16 MB
    float* colPart = (float*)(w + (size_t)32 * 1024 * 1024);   // 262144 f (1 MB)
    float* rowPart = colPart + 262144;                         // 131072 f (0.5 MB)
    float* diagPart = rowPart + 131072;                        // 1024 f
    float* scalars = diagPart + 1024;                          // [logSum]
    unsigned int* counter = (unsigned int*)(scalars + 1);

    hipLaunchKernelGGL(nrm_kernel, dim3(1024), dim3(256), 0, stream,
                       A, B, E1f, E2f, diagPart, scalars, counter);
    hipLaunchKernelGGL(gemm_kernel, dim3(512), dim3(256), 0, stream,
                       (const bf16x8*)E1f, (const uint4*)E2f, colPart, rowPart);
    hipLaunchKernelGGL(fin_kernel, dim3(64), dim3(256), 0, stream,
                       colPart, rowPart, diagPart, scalars, counter, (float*)d_out);
}